// Round 8
// baseline (145.638 us; speedup 1.0000x reference)
//
#include <hip/hip_runtime.h>
#include <math.h>

#define DM    512
#define LSEQ  256
#define NB    2
#define NH    8
#define DK    64
#define SCALEF 0.125f   // 64^-0.5

// ---------------------------------------------------------------------------
// Kernel A: fused QKV GEMM (128x128 tile, 8x8/thread, split-k=8) + gating.
// Grid 400 blocks:
//   bx < 384: ks = bx&7 (k-split, 64-k range), t = bx>>3: rt = t/12 (row
//     tile 0..3), ct = t%12 -> op = ct>>2 (0 Q trop, 1 K trop, 2 V fma),
//     col tile (ct&3)*128. Single 64-k chunk. Partials to P1[ks][512][1536].
//   bx >= 384: gating, 32 rows each.
// LDS: Xs[64][128] k-major (reads broadcast over ty -> banks 0/8/16/24,
// free). Wp[32][256] kk-PAIR-INTERLEAVED: Wp[kp][c*2+p] = W[2kp+p][c], so an
// 8-col thread reads 4 b128 at stride-16 floats -> banks {0,16}, 2-way free
// (plain k-major 8-col reads would be 4-way conflicted).
// Per k-pair: 8 b128 (96cy LDS) vs 128 MACs (384cy trop VALU = 96cy/SIMD
// share) -> LDS pipe exactly balanced with 4 SIMDs/CU.
// ---------------------------------------------------------------------------
__global__ __launch_bounds__(256) void qkvg_kernel(
    const float* __restrict__ x,
    const float* __restrict__ qW, const float* __restrict__ kW,
    const float* __restrict__ vW,
    const float* __restrict__ gW, const float* __restrict__ gb,
    float* __restrict__ P1, float* __restrict__ go)
{
    const int tid = threadIdx.x;
    const int bx  = blockIdx.x;

    if (bx >= 384) {  // ---- gating ----
        const int gx  = bx - 384;
        const int row = gx * 32 + (tid >> 3);
        const int h   = tid & 7;
        const float4* xr = (const float4*)(x  + row * DM);
        const float4* wr = (const float4*)(gW + h  * DM);
        float acc = 0.f;
        #pragma unroll 8
        for (int i = 0; i < DM / 4; ++i) {
            float4 a = xr[i], w = wr[i];
            acc = fmaf(a.x, w.x, acc);
            acc = fmaf(a.y, w.y, acc);
            acc = fmaf(a.z, w.z, acc);
            acc = fmaf(a.w, w.w, acc);
        }
        acc += gb[h];
        go[row * NH + h] = 1.f / (1.f + __expf(-acc));
        return;
    }

    const int ks = bx & 7;
    const int t  = bx >> 3;          // 0..47
    const int rt = t / 12;           // 0..3
    const int ct = t % 12;           // 0..11
    const int op = ct >> 2;          // 0 Q, 1 K, 2 V
    const int row0  = rt * 128;
    const int col0m = (ct & 3) * 128;
    const int kbase = ks * 64;

    const float* __restrict__ W = (op == 0) ? qW : (op == 1) ? kW : vW;
    const bool trop = (op < 2);

    __shared__ float Xs[64][128];
    __shared__ float Wp[32][256];

    const int sr = tid & 127;        // x-row / w-col
    const int sq = tid >> 7;         // 0..1 -> 32-k window

    {   // ---- stage (single 64-k chunk) ----
        const float* xp = x + (size_t)(row0  + sr) * DM + kbase + sq * 32;
        const float* wp = W + (size_t)(col0m + sr) * DM + kbase + sq * 32;
        #pragma unroll
        for (int i = 0; i < 8; ++i) {
            float4 xv = *(const float4*)(xp + i * 4);
            float4 wv = *(const float4*)(wp + i * 4);
            const int kk = sq * 32 + i * 4;
            Xs[kk + 0][sr] = xv.x;  Xs[kk + 1][sr] = xv.y;
            Xs[kk + 2][sr] = xv.z;  Xs[kk + 3][sr] = xv.w;
            const int kp = (kk >> 1);            // = sq*16 + 2i
            *(float2*)&Wp[kp    ][2 * sr] = make_float2(wv.x, wv.y);
            *(float2*)&Wp[kp + 1][2 * sr] = make_float2(wv.z, wv.w);
        }
    }
    __syncthreads();

    const int ty = tid >> 4, tx = tid & 15;   // rows ty*8, cols tx*8
    const float init = trop ? -INFINITY : 0.f;
    float acc[8][8];
    #pragma unroll
    for (int i = 0; i < 8; ++i)
        #pragma unroll
        for (int j = 0; j < 8; ++j) acc[i][j] = init;

    #pragma unroll 2
    for (int kp = 0; kp < 32; ++kp) {
        const int kk = kp * 2;
        const float4 xa0 = *(const float4*)&Xs[kk    ][ty * 8];
        const float4 xa1 = *(const float4*)&Xs[kk    ][ty * 8 + 4];
        const float4 xb0 = *(const float4*)&Xs[kk + 1][ty * 8];
        const float4 xb1 = *(const float4*)&Xs[kk + 1][ty * 8 + 4];
        const float4 wq[4] = {
            *(const float4*)&Wp[kp][tx * 16     ],
            *(const float4*)&Wp[kp][tx * 16 +  4],
            *(const float4*)&Wp[kp][tx * 16 +  8],
            *(const float4*)&Wp[kp][tx * 16 + 12] };
        const float x0[8] = {xa0.x,xa0.y,xa0.z,xa0.w,xa1.x,xa1.y,xa1.z,xa1.w};
        const float x1[8] = {xb0.x,xb0.y,xb0.z,xb0.w,xb1.x,xb1.y,xb1.z,xb1.w};
        if (trop) {
            #pragma unroll
            for (int i = 0; i < 4; ++i)
                #pragma unroll
                for (int r = 0; r < 8; ++r) {
                    acc[r][2*i  ] = fmaxf(fmaxf(acc[r][2*i  ], x0[r]+wq[i].x),
                                          x1[r]+wq[i].y);
                    acc[r][2*i+1] = fmaxf(fmaxf(acc[r][2*i+1], x0[r]+wq[i].z),
                                          x1[r]+wq[i].w);
                }
        } else {
            #pragma unroll
            for (int i = 0; i < 4; ++i)
                #pragma unroll
                for (int r = 0; r < 8; ++r) {
                    acc[r][2*i  ] = fmaf(x0[r], wq[i].x, acc[r][2*i  ]);
                    acc[r][2*i  ] = fmaf(x1[r], wq[i].y, acc[r][2*i  ]);
                    acc[r][2*i+1] = fmaf(x0[r], wq[i].z, acc[r][2*i+1]);
                    acc[r][2*i+1] = fmaf(x1[r], wq[i].w, acc[r][2*i+1]);
                }
        }
    }

    const int gcol = op * 512 + col0m + tx * 8;
    #pragma unroll
    for (int r = 0; r < 8; ++r) {
        const int grow = row0 + ty * 8 + r;
        float* dst = &P1[((size_t)ks * 512 + grow) * 1536 + gcol];
        *(float4*)dst       = make_float4(acc[r][0], acc[r][1], acc[r][2], acc[r][3]);
        *(float4*)(dst + 4) = make_float4(acc[r][4], acc[r][5], acc[r][6], acc[r][7]);
    }
}

// ---------------------------------------------------------------------------
// Reduce 1: fold 8 k-split partials (max for Q/K, add for V) + bias.
// 768 blocks x 256 thr, one float4 per thread.
// ---------------------------------------------------------------------------
__global__ __launch_bounds__(256) void qkv_reduce_kernel(
    const float* __restrict__ P1,
    const float* __restrict__ qb, const float* __restrict__ kb,
    const float* __restrict__ vb,
    float* __restrict__ Qo, float* __restrict__ Ko, float* __restrict__ Vo)
{
    const int e   = blockIdx.x * 256 + threadIdx.x;  // float4 index
    const int row = e / 384;
    const int col = (e % 384) * 4;
    const size_t base = (size_t)row * 1536 + col;

    float4 p[8];
    #pragma unroll
    for (int s = 0; s < 8; ++s)
        p[s] = *(const float4*)&P1[base + (size_t)s * 786432];

    if (col < 1024) {  // tropical: max over splits
        float4 r = p[0];
        #pragma unroll
        for (int s = 1; s < 8; ++s) {
            r.x = fmaxf(r.x, p[s].x); r.y = fmaxf(r.y, p[s].y);
            r.z = fmaxf(r.z, p[s].z); r.w = fmaxf(r.w, p[s].w);
        }
        if (col < 512) {
            float4 b = *(const float4*)&qb[col];
            r.x += b.x; r.y += b.y; r.z += b.z; r.w += b.w;
            *(float4*)&Qo[(size_t)row * DM + col] = r;
        } else {
            float4 b = *(const float4*)&kb[col - 512];
            r.x += b.x; r.y += b.y; r.z += b.z; r.w += b.w;
            *(float4*)&Ko[(size_t)row * DM + col - 512] = r;
        }
    } else {           // V: sum over splits
        float4 b = *(const float4*)&vb[col - 1024];
        float4 r = b;
        #pragma unroll
        for (int s = 0; s < 8; ++s) {
            r.x += p[s].x; r.y += p[s].y; r.z += p[s].z; r.w += p[s].w;
        }
        *(float4*)&Vo[(size_t)row * DM + col - 1024] = r;
    }
}

// ---------------------------------------------------------------------------
// Kernel B: attention. Block = (q-tile 16, bh), 512 threads.
// Score: Q in registers, K staged k-major in As; thread (ty,tx) owns 2 kcols.
// Softmax: 32-lane shfl groups. PV: 4-way k-split (kh,kq); thread owns
// (2 rows x 4 dcols x 64 k); V double-staged in As/Bs; 4-partial combine
// reuses As (dead after score).
// ---------------------------------------------------------------------------
__global__ __launch_bounds__(512) void attn_kernel(
    const float* __restrict__ Q, const float* __restrict__ K,
    const float* __restrict__ V, const float* __restrict__ g,
    const float* __restrict__ temp,
    float* __restrict__ attn_out, float* __restrict__ hout)
{
    const int tid = threadIdx.x;
    const int bh  = blockIdx.y;
    const int b   = bh >> 3, h = bh & 7;
    const int q0  = blockIdx.x * 16;
    const int ty  = tid >> 5;        // 0..15 q-row
    const int tx  = tid & 31;        // 0..31

    __shared__ float As[64][68];     // Kd (score) -> V tile A (PV) -> combine
    __shared__ float Bs[64][68];     // V tile B
    __shared__ float Ss[16][260];

    // Q row -> 16 float4 registers
    const float* qrow = Q + (size_t)(b * LSEQ + q0 + ty) * DM + h * DK;
    float4 qreg[16];
    #pragma unroll
    for (int i = 0; i < 16; ++i) qreg[i] = *(const float4*)(qrow + i * 4);

    const float gq   = g[(b * LSEQ + q0 + ty) * NH + h];
    const float invt = SCALEF / temp[h];

    const int ksr = tid & 63;   // K staging: kcol
    const int ksq = tid >> 6;   // 0..7 -> 8-d window

    // ---- scores ----
    for (int kt = 0; kt < 4; ++kt) {
        __syncthreads();
        {   // stage K transposed: As[d][kcol]
            const float* kp = K + (size_t)(b * LSEQ + kt * 64 + ksr) * DM
                              + h * DK + ksq * 8;
            #pragma unroll
            for (int i = 0; i < 2; ++i) {
                float4 v = *(const float4*)(kp + i * 4);
                const int d = ksq * 8 + i * 4;
                As[d + 0][ksr] = v.x;  As[d + 1][ksr] = v.y;
                As[d + 2][ksr] = v.z;  As[d + 3][ksr] = v.w;
            }
        }
        __syncthreads();
        float d0 = 0.f, d1 = 0.f;
        float t0 = -INFINITY, t1 = -INFINITY;
        #pragma unroll
        for (int k4 = 0; k4 < 16; ++k4) {
            const float4 q4 = qreg[k4];
            float2 ka = *(const float2*)&As[k4 * 4 + 0][tx * 2];
            float2 kb = *(const float2*)&As[k4 * 4 + 1][tx * 2];
            float2 kc = *(const float2*)&As[k4 * 4 + 2][tx * 2];
            float2 kd = *(const float2*)&As[k4 * 4 + 3][tx * 2];
            d0 = fmaf(q4.x, ka.x, d0); d0 = fmaf(q4.y, kb.x, d0);
            d0 = fmaf(q4.z, kc.x, d0); d0 = fmaf(q4.w, kd.x, d0);
            d1 = fmaf(q4.x, ka.y, d1); d1 = fmaf(q4.y, kb.y, d1);
            d1 = fmaf(q4.z, kc.y, d1); d1 = fmaf(q4.w, kd.y, d1);
            t0 = fmaxf(fmaxf(t0, q4.x + ka.x), q4.y + kb.x);
            t0 = fmaxf(fmaxf(t0, q4.z + kc.x), q4.w + kd.x);
            t1 = fmaxf(fmaxf(t1, q4.x + ka.y), q4.y + kb.y);
            t1 = fmaxf(fmaxf(t1, q4.z + kc.y), q4.w + kd.y);
        }
        const float gi = 1.f - gq;
        *(float2*)&Ss[ty][kt * 64 + tx * 2] = make_float2(
            (gq * t0 + gi * d0) * invt, (gq * t1 + gi * d1) * invt);
    }
    __syncthreads();

    // ---- softmax: row ty, 32 lanes x 8 elems ----
    {
        float m = -INFINITY;
        #pragma unroll
        for (int j = 0; j < 8; ++j) m = fmaxf(m, Ss[ty][tx + 32 * j]);
        #pragma unroll
        for (int o = 16; o; o >>= 1) m = fmaxf(m, __shfl_xor(m, o));
        float s = 0.f;
        #pragma unroll
        for (int j = 0; j < 8; ++j) {
            const float e = __expf(Ss[ty][tx + 32 * j] - m);
            Ss[ty][tx + 32 * j] = e;
            s += e;
        }
        #pragma unroll
        for (int o = 16; o; o >>= 1) s += __shfl_xor(s, o);
        const float rs = 1.f / s;
        #pragma unroll
        for (int j = 0; j < 8; ++j) Ss[ty][tx + 32 * j] *= rs;
    }
    __syncthreads();

    // ---- write attn tile ----
    {
        float* dst = attn_out + (size_t)(bh * LSEQ + q0) * LSEQ;
        #pragma unroll
        for (int i = 0; i < 2; ++i) {
            const int f   = i * 2048 + tid * 4;
            const int row = f >> 8, col = f & 255;
            *(float4*)&dst[f] = *(const float4*)&Ss[row][col];
        }
    }

    // ---- PV: 4-way k-split. g4 = tid>>7: kh = g4>>1 (tile pair),
    //      kq = g4&1 (32-k half). Thread owns rows {rp*2, rp*2+1}, cols d4*4.
    const int g4 = tid >> 7;          // 0..3
    const int kh = g4 >> 1, kq = g4 & 1;
    const int rp = (tid >> 4) & 7;    // row pair
    const int d4 = tid & 15;          // d-col group
    float o00=0.f,o01=0.f,o02=0.f,o03=0.f;
    float o10=0.f,o11=0.f,o12=0.f,o13=0.f;

    const int vtile = tid >> 8;       // 0/1: stage As or Bs
    const int vr    = tid & 63;
    const int vw    = (tid >> 6) & 3; // 16-float window

    for (int p = 0; p < 2; ++p) {
        __syncthreads();
        {   // stage V: As <- tile p, Bs <- tile 2+p
            const int tsrc = vtile ? (2 + p) : p;
            const float* vp = V + (size_t)(b * LSEQ + tsrc * 64 + vr) * DM
                              + h * DK + vw * 16;
            float* vdst = vtile ? &Bs[vr][vw * 16] : &As[vr][vw * 16];
            #pragma unroll
            for (int i = 0; i < 4; ++i)
                *(float4*)(vdst + i * 4) = *(const float4*)(vp + i * 4);
        }
        __syncthreads();
        const int kt = kh * 2 + p;
        const float* vb = kh ? &Bs[0][0] : &As[0][0];
        const int koff = kt * 64 + kq * 32;
        #pragma unroll 4
        for (int k4 = 0; k4 < 8; ++k4) {
            const int kl = kq * 32 + k4 * 4;
            float4 a0 = *(const float4*)&Ss[rp * 2    ][koff + k4 * 4];
            float4 a1 = *(const float4*)&Ss[rp * 2 + 1][koff + k4 * 4];
            float4 v0 = *(const float4*)&vb[(kl    ) * 68 + d4 * 4];
            float4 v1 = *(const float4*)&vb[(kl + 1) * 68 + d4 * 4];
            float4 v2 = *(const float4*)&vb[(kl + 2) * 68 + d4 * 4];
            float4 v3 = *(const float4*)&vb[(kl + 3) * 68 + d4 * 4];
            o00 = fmaf(a0.x, v0.x, o00); o00 = fmaf(a0.y, v1.x, o00);
            o00 = fmaf(a0.z, v2.x, o00); o00 = fmaf(a0.w, v3.x, o00);
            o01 = fmaf(a0.x, v0.y, o01); o01 = fmaf(a0.y, v1.y, o01);
            o01 = fmaf(a0.z, v2.y, o01); o01 = fmaf(a0.w, v3.y, o01);
            o02 = fmaf(a0.x, v0.z, o02); o02 = fmaf(a0.y, v1.z, o02);
            o02 = fmaf(a0.z, v2.z, o02); o02 = fmaf(a0.w, v3.z, o02);
            o03 = fmaf(a0.x, v0.w, o03); o03 = fmaf(a0.y, v1.w, o03);
            o03 = fmaf(a0.z, v2.w, o03); o03 = fmaf(a0.w, v3.w, o03);
            o10 = fmaf(a1.x, v0.x, o10); o10 = fmaf(a1.y, v1.x, o10);
            o10 = fmaf(a1.z, v2.x, o10); o10 = fmaf(a1.w, v3.x, o10);
            o11 = fmaf(a1.x, v0.y, o11); o11 = fmaf(a1.y, v1.y, o11);
            o11 = fmaf(a1.z, v2.y, o11); o11 = fmaf(a1.w, v3.y, o11);
            o12 = fmaf(a1.x, v0.z, o12); o12 = fmaf(a1.y, v1.z, o12);
            o12 = fmaf(a1.z, v2.z, o12); o12 = fmaf(a1.w, v3.z, o12);
            o13 = fmaf(a1.x, v0.w, o13); o13 = fmaf(a1.y, v1.w, o13);
            o13 = fmaf(a1.z, v2.w, o13); o13 = fmaf(a1.w, v3.w, o13);
        }
    }
    // ---- combine 4 partials (reuse As; all V reads done) ----
    __syncthreads();
    if (g4 > 0) {
        const int cr = (g4 - 1) * 16 + rp * 2;
        *(float4*)&As[cr    ][d4 * 4] = make_float4(o00, o01, o02, o03);
        *(float4*)&As[cr + 1][d4 * 4] = make_float4(o10, o11, o12, o13);
    }
    __syncthreads();
    if (g4 == 0) {
        #pragma unroll
        for (int s = 0; s < 3; ++s) {
            float4 p0 = *(const float4*)&As[s * 16 + rp * 2    ][d4 * 4];
            float4 p1 = *(const float4*)&As[s * 16 + rp * 2 + 1][d4 * 4];
            o00 += p0.x; o01 += p0.y; o02 += p0.z; o03 += p0.w;
            o10 += p1.x; o11 += p1.y; o12 += p1.z; o13 += p1.w;
        }
        const size_t r0 = (size_t)(b * LSEQ + q0 + rp * 2) * DM + h * DK + d4 * 4;
        *(float4*)&hout[r0]      = make_float4(o00, o01, o02, o03);
        *(float4*)&hout[r0 + DM] = make_float4(o10, o11, o12, o13);
    }
}

// ---------------------------------------------------------------------------
// Kernel C: oproj partial, 128x128 tile, 8x8/thread, split-k=16 (32-k range).
// bx: ks = bx&15, t = bx>>4: row tile t>>2, col tile t&3.
// Same balanced LDS layout as kernel A. Writes P2[ks][512][512].
// ---------------------------------------------------------------------------
__global__ __launch_bounds__(256) void oproj_kernel(
    const float* __restrict__ hout,
    const float* __restrict__ oW,
    float* __restrict__ P2)
{
    const int tid = threadIdx.x;
    const int bx  = blockIdx.x;
    const int ks  = bx & 15;
    const int t   = bx >> 4;
    const int row0 = (t >> 2) * 128;
    const int col0 = (t & 3) * 128;
    const int kbase = ks * 32;

    __shared__ float Xs[32][128];
    __shared__ float Wp[16][256];

    const int sr = tid & 127;
    const int sq = tid >> 7;         // 0..1 -> 16-k window

    {
        const float* xp = hout + (size_t)(row0 + sr) * DM + kbase + sq * 16;
        const float* wp = oW   + (size_t)(col0 + sr) * DM + kbase + sq * 16;
        #pragma unroll
        for (int i = 0; i < 4; ++i) {
            float4 xv = *(const float4*)(xp + i * 4);
            float4 wv = *(const float4*)(wp + i * 4);
            const int kk = sq * 16 + i * 4;
            Xs[kk + 0][sr] = xv.x;  Xs[kk + 1][sr] = xv.y;
            Xs[kk + 2][sr] = xv.z;  Xs[kk + 3][sr] = xv.w;
            const int kp = (kk >> 1);
            *(float2*)&Wp[kp    ][2 * sr] = make_float2(wv.x, wv.y);
            *(float2*)&Wp[kp + 1][2 * sr] = make_float2(wv.z, wv.w);
        }
    }
    __syncthreads();

    const int ty = tid >> 4, tx = tid & 15;
    float acc[8][8] = {};

    #pragma unroll 2
    for (int kp = 0; kp < 16; ++kp) {
        const int kk = kp * 2;
        const float4 xa0 = *(const float4*)&Xs[kk    ][ty * 8];
        const float4 xa1 = *(const float4*)&Xs[kk    ][ty * 8 + 4];
        const float4 xb0 = *(const float4*)&Xs[kk + 1][ty * 8];
        const float4 xb1 = *(const float4*)&Xs[kk + 1][ty * 8 + 4];
        const float4 wq[4] = {
            *(const float4*)&Wp[kp][tx * 16     ],
            *(const float4*)&Wp[kp][tx * 16 +  4],
            *(const float4*)&Wp[kp][tx * 16 +  8],
            *(const float4*)&Wp[kp][tx * 16 + 12] };
        const float x0[8] = {xa0.x,xa0.y,xa0.z,xa0.w,xa1.x,xa1.y,xa1.z,xa1.w};
        const float x1[8] = {xb0.x,xb0.y,xb0.z,xb0.w,xb1.x,xb1.y,xb1.z,xb1.w};
        #pragma unroll
        for (int i = 0; i < 4; ++i)
            #pragma unroll
            for (int r = 0; r < 8; ++r) {
                acc[r][2*i  ] = fmaf(x0[r], wq[i].x, acc[r][2*i  ]);
                acc[r][2*i  ] = fmaf(x1[r], wq[i].y, acc[r][2*i  ]);
                acc[r][2*i+1] = fmaf(x0[r], wq[i].z, acc[r][2*i+1]);
                acc[r][2*i+1] = fmaf(x1[r], wq[i].w, acc[r][2*i+1]);
            }
    }

    #pragma unroll
    for (int r = 0; r < 8; ++r) {
        const int grow = row0 + ty * 8 + r;
        float* dst = &P2[((size_t)ks * 512 + grow) * 512 + col0 + tx * 8];
        *(float4*)dst       = make_float4(acc[r][0], acc[r][1], acc[r][2], acc[r][3]);
        *(float4*)(dst + 4) = make_float4(acc[r][4], acc[r][5], acc[r][6], acc[r][7]);
    }
}

// ---------------------------------------------------------------------------
// Reduce 2: fold 16 oproj partials + ob -> out. 256 blocks x 256 thr.
// ---------------------------------------------------------------------------
__global__ __launch_bounds__(256) void oproj_reduce_kernel(
    const float* __restrict__ P2, const float* __restrict__ ob,
    float* __restrict__ out)
{
    const int e   = blockIdx.x * 256 + threadIdx.x;  // float4 index
    const int row = e >> 7;
    const int col = (e & 127) * 4;
    const size_t base = (size_t)row * 512 + col;

    float4 b = *(const float4*)&ob[col];
    float4 r = b;
    #pragma unroll
    for (int s = 0; s < 16; ++s) {
        float4 p = *(const float4*)&P2[base + (size_t)s * 262144];
        r.x += p.x; r.y += p.y; r.z += p.z; r.w += p.w;
    }
    *(float4*)&out[base] = r;
}

extern "C" void kernel_launch(void* const* d_in, const int* in_sizes, int n_in,
                              void* d_out, int out_size, void* d_ws, size_t ws_size,
                              hipStream_t stream)
{
    const float* x    = (const float*)d_in[0];
    const float* qW   = (const float*)d_in[1];
    const float* qb   = (const float*)d_in[2];
    const float* kW   = (const float*)d_in[3];
    const float* kb   = (const float*)d_in[4];
    const float* vW   = (const float*)d_in[5];
    const float* vb   = (const float*)d_in[6];
    const float* oW   = (const float*)d_in[7];
    const float* ob   = (const float*)d_in[8];
    const float* gW   = (const float*)d_in[9];
    const float* gb   = (const float*)d_in[10];
    const float* temp = (const float*)d_in[11];

    float* out      = (float*)d_out;                 // (B,L,512)
    float* attn_out = out + NB * LSEQ * DM;          // (B,H,L,L)

    float* ws   = (float*)d_ws;
    float* Qo   = ws;                                // 262144 floats
    float* Ko   = Qo + NB * LSEQ * DM;               // 262144
    float* Vo   = Ko + NB * LSEQ * DM;               // 262144
    float* go   = Vo + NB * LSEQ * DM;               // 4096
    float* hout = go + NB * LSEQ * NH;               // 262144 (merged B,L,512)
    float* P1   = hout + NB * LSEQ * DM;             // 8*512*1536 = 6291456
    float* P2   = P1;                                // aliases P1 (dead by then)

    qkvg_kernel<<<dim3(400), 256, 0, stream>>>(
        x, qW, kW, vW, gW, gb, P1, go);
    qkv_reduce_kernel<<<dim3(768), 256, 0, stream>>>(
        P1, qb, kb, vb, Qo, Ko, Vo);
    attn_kernel<<<dim3(16, 16), 512, 0, stream>>>(
        Qo, Ko, Vo, go, temp, attn_out, hout);
    oproj_kernel<<<dim3(256), 256, 0, stream>>>(
        hout, oW, P2);
    oproj_reduce_kernel<<<dim3(256), 256, 0, stream>>>(
        P2, ob, out);
}